// Round 5
// baseline (213.116 us; speedup 1.0000x reference)
//
#include <hip/hip_runtime.h>

#define NB 32
#define NTDUR 512                      // durations per batch
#define NT 256                         // threads per block
#define ND 384
#define MAX_OUT 3584                   // NTDUR * (DUR_MAX-1)
#define NV (ND / 4)                    // 96 float4 per row
#define NWIN 32                        // output windows per batch
#define WPOS (MAX_OUT / NWIN)          // 112 output positions per block
#define NBLK (NB * NWIN)               // 1024 blocks (4 per CU, %8==0)
#define VPT (WPOS * NV / NT)           // 42 float4 per thread

typedef float f32x4 __attribute__((ext_vector_type(4)));  // native vec: nt-store OK

// Fused single kernel, 4 blocks/CU. Race-proof LDS table build:
// sentinel-init before the scan barrier, disjoint-interval scatter after it.
// Zero-tail rows issue no global read; output stored non-temporally.
__global__ __launch_bounds__(NT) void lr_fused(
    const int* __restrict__ dur, const f32x4* __restrict__ in,
    f32x4* __restrict__ out)
{
    __shared__ int wsum[NT / 64];
    __shared__ int ridx[WPOS];

    // XCD swizzle: 128 consecutive logical blocks (= 4 batches) per XCD
    // -> per-XCD input slice 3 MB (L2-resident). Bijective (1024 % 8 == 0).
    const unsigned bid = blockIdx.x;
    const unsigned l   = (bid & 7u) * (NBLK / 8u) + (bid >> 3);
    const int b  = (int)(l >> 5);       // batch
    const int wb = (int)(l & 31u);      // window within batch
    const int p0 = wb * WPOS;

    const int t    = threadIdx.x;
    const int lane = t & 63;
    const int w    = t >> 6;

    // sentinel-init the whole window BEFORE the scan barrier (each slot
    // written by exactly one thread; scatter only overwrites valid slots)
    if (t < WPOS) ridx[t] = -1;

    // each thread owns 2 consecutive source rows: e0 = 2t, e1 = 2t+1
    const int2 dd = ((const int2*)dur)[b * (NTDUR / 2) + t];
    const int d0 = dd.x > 0 ? dd.x : 0;   // patched = max(d,0)
    const int d1 = dd.y > 0 ? dd.y : 0;
    const int s  = d0 + d1;

    // wave-level inclusive shfl scan of pair-sums (6 steps, no barriers)
    int v = s;
    #pragma unroll
    for (int off = 1; off < 64; off <<= 1) {
        int u = __shfl_up(v, off);
        if (lane >= off) v += u;
    }
    if (lane == 63) wsum[w] = v;
    __syncthreads();

    // cross-wave combine: 4 broadcast LDS reads per thread, no serial section
    int prev = 0;
    #pragma unroll
    for (int i = 0; i < NT / 64; ++i) prev += (i < w) ? wsum[i] : 0;
    const int excl = prev + v - s;        // exclusive prefix before e0

    // scatter source float4-bases into this window's slots (disjoint intervals)
    const int row0 = b * NTDUR + 2 * t;
    const int en0  = excl + d0;           // e0 covers [excl, en0), e1 [en0, en0+d1)
    {
        int lo = excl - p0; if (lo < 0) lo = 0;
        int hi = en0  - p0; if (hi > WPOS) hi = WPOS;
        const int src = row0 * NV;
        for (int j = lo; j < hi; ++j) ridx[j] = src;
    }
    {
        int lo = en0 - p0;      if (lo < 0) lo = 0;
        int hi = en0 + d1 - p0; if (hi > WPOS) hi = WPOS;
        const int src = (row0 + 1) * NV;
        for (int j = lo; j < hi; ++j) ridx[j] = src;
    }
    __syncthreads();

    // coalesced copy: 112 rows x 96 float4 = 10752 float4 / 256 thr = 42 each
    f32x4* ob = out + ((size_t)b * MAX_OUT + p0) * NV;
    for (int i = 0; i < VPT; ++i) {
        const int g = i * NT + t;
        const int r = g / NV;             // compile-time magic-mul
        const int c = g - r * NV;
        const int sv = ridx[r];           // LDS, broadcast within wave
        f32x4 val = (f32x4)(0.f);
        if (sv >= 0) val = in[sv + c];    // predicated: zero rows issue no read
        __builtin_nontemporal_store(val, &ob[g]);
    }
}

extern "C" void kernel_launch(void* const* d_in, const int* in_sizes, int n_in,
                              void* d_out, int out_size, void* d_ws, size_t ws_size,
                              hipStream_t stream)
{
    const float* x   = (const float*)d_in[0];
    const int*   dur = (const int*)d_in[1];
    float* out = (float*)d_out;

    lr_fused<<<NBLK, NT, 0, stream>>>(dur, (const f32x4*)x, (f32x4*)out);
}